// Round 2
// baseline (217.169 us; speedup 1.0000x reference)
//
#include <hip/hip_runtime.h>
#include <hip/hip_fp16.h>

#define NNODES 4096
#define NEDGES 500000
#define NPAIRS 2000000
#define EDIM   16
#define LMAX   5

typedef int v4i __attribute__((ext_vector_type(4)));
typedef float v4f __attribute__((ext_vector_type(4)));

__device__ __forceinline__ v4i ntload4(const int* p) {
  return __builtin_nontemporal_load((const v4i*)p);
}
__device__ __forceinline__ void ntstore4(float* p, float x, float y, float z, float w) {
  v4f t = {x, y, z, w};
  __builtin_nontemporal_store(t, (v4f*)p);
}

// ---------------------------------------------------------------------------
// Kernel 0: dots[l*NEDGES + e] = fp16(dot(edge_attr[e,:], edge_weights[l,:]))
// 2 edges/thread -> half2 stores. fp16 halves the downstream gather footprint
// (5MB total, ~L2-resident/XCD).
// ---------------------------------------------------------------------------
__global__ __launch_bounds__(256) void dots_kernel(
    const float* __restrict__ edge_attr,
    const float* __restrict__ ew,
    __half* __restrict__ dots) {
  __shared__ float w[LMAX * EDIM];
  int tid = threadIdx.x;
  if (tid < LMAX * EDIM) w[tid] = ew[tid];
  __syncthreads();

  int e0 = (blockIdx.x * 256 + tid) * 2;  // NEDGES even -> e0+1 always valid
  if (e0 >= NEDGES) return;

  const float4* ra = (const float4*)(edge_attr + (size_t)e0 * EDIM);
  float4 a0 = ra[0], a1 = ra[1], a2 = ra[2], a3 = ra[3];
  float4 b0 = ra[4], b1 = ra[5], b2 = ra[6], b3 = ra[7];  // edge e0+1
  float va[16] = {a0.x, a0.y, a0.z, a0.w, a1.x, a1.y, a1.z, a1.w,
                  a2.x, a2.y, a2.z, a2.w, a3.x, a3.y, a3.z, a3.w};
  float vb[16] = {b0.x, b0.y, b0.z, b0.w, b1.x, b1.y, b1.z, b1.w,
                  b2.x, b2.y, b2.z, b2.w, b3.x, b3.y, b3.z, b3.w};
#pragma unroll
  for (int l = 0; l < LMAX; ++l) {
    float da = 0.f, db = 0.f;
#pragma unroll
    for (int k = 0; k < EDIM; ++k) {
      da += va[k] * w[l * EDIM + k];
      db += vb[k] * w[l * EDIM + k];
    }
    __half2 h;
    h.x = __float2half(da);
    h.y = __float2half(db);
    *(__half2*)(dots + (size_t)l * NEDGES + e0) = h;  // e0 even -> 4B aligned
  }
}

// ---------------------------------------------------------------------------
// Fused mean + transpose, occupancy-fixed.
// 1024-thread blocks: the 512 gather-heavy tiles (dst_tile 0..7) hold
// 512 x 16 = 8192 waves = 32 waves/CU (100%) during the gather phase --
// the R1 version had only 8 waves/CU (Occupancy 31%) because the heavy work
// was packed into 512 x 4-wave blocks. Each thread keeps one 4-pair chunk:
// 5 NT dwordx4 idx loads + up to 20 independent 2B gathers in flight.
// Dispatch order interleaves heavy/zero 1:1 over the first 1024 blocks so
// pure-write zero tiles stream HBM writes under heavy-wave vmcnt stalls.
// All out stores are non-temporal (64MB never re-read; protect dots in L2).
// ---------------------------------------------------------------------------
__device__ __forceinline__ float pair_mean(
    const __half* __restrict__ dots, int len,
    int i0, int i1, int i2, int i3, int i4) {
  len = min(max(len, 0), LMAX);
  float v0 = (len > 0) ? __half2float(dots[i0]) : 0.f;
  float v1 = (len > 1) ? __half2float(dots[1 * NEDGES + i1]) : 0.f;
  float v2 = (len > 2) ? __half2float(dots[2 * NEDGES + i2]) : 0.f;
  float v3 = (len > 3) ? __half2float(dots[3 * NEDGES + i3]) : 0.f;
  float v4 = (len > 4) ? __half2float(dots[4 * NEDGES + i4]) : 0.f;
  float s = ((v0 + v1) + (v2 + v3)) + v4;
  return (len > 0) ? s / (float)len : 0.f;
}

__global__ __launch_bounds__(1024) void fused_mean_transpose(
    const int* __restrict__ path_idx,
    const int* __restrict__ path_lens,
    const __half* __restrict__ dots,
    float* __restrict__ out) {
  // Block-id remap: heavy tiles are (dst_t, src_t) with dst_t in [0,8);
  // interleave them 1:1 with zero tiles across the first 1024 dispatched ids.
  int bid = blockIdx.x;
  int dst_t, src_t;
  bool heavy;
  if (bid < 1024) {
    heavy = (bid & 1);
    int k = bid >> 1;                     // 0..511
    if (heavy) { dst_t = k & 7;        src_t = k >> 3; }
    else       { dst_t = 8 + (k >> 6); src_t = k & 63; }
  } else {
    heavy = false;
    int z = bid - 512;                    // 512..3583
    dst_t = 8 + (z >> 6);
    src_t = z & 63;
  }
  const int src0 = src_t * 64;
  const int dst0 = dst_t * 64;
  const int tid = threadIdx.x;            // 0..1023
  const int a = tid >> 4;                 // 0..63
  const int c = tid & 15;                 // float4 col group

  if (!heavy) {                           // pure-zero tile: stream writes
    ntstore4(out + (size_t)(src0 + a) * NNODES + dst0 + 4 * c, 0.f, 0.f, 0.f, 0.f);
    return;
  }

  __shared__ float tile[64][65];

  {
    int p = (dst0 + a) * NNODES + src0 + 4 * c;  // multiple of 4
    float4 v = {0.f, 0.f, 0.f, 0.f};
    if (p < NPAIRS) {  // NPAIRS%4==0 -> all 4 pairs valid together
      v4i ln = ntload4(path_lens + p);
      const int* q = path_idx + (size_t)p * LMAX;  // 16B aligned (p%4==0)
      v4i A = ntload4(q);
      v4i B = ntload4(q + 4);
      v4i C = ntload4(q + 8);
      v4i D = ntload4(q + 12);
      v4i E = ntload4(q + 16);
      v.x = pair_mean(dots, ln[0], A[0], A[1], A[2], A[3], B[0]);
      v.y = pair_mean(dots, ln[1], B[1], B[2], B[3], C[0], C[1]);
      v.z = pair_mean(dots, ln[2], C[2], C[3], D[0], D[1], D[2]);
      v.w = pair_mean(dots, ln[3], D[3], E[0], E[1], E[2], E[3]);
    }
    tile[a][4 * c + 0] = v.x;
    tile[a][4 * c + 1] = v.y;
    tile[a][4 * c + 2] = v.z;
    tile[a][4 * c + 3] = v.w;
  }
  __syncthreads();
  {
    float x = tile[4 * c + 0][a];
    float y = tile[4 * c + 1][a];
    float z = tile[4 * c + 2][a];
    float w = tile[4 * c + 3][a];
    ntstore4(out + (size_t)(src0 + a) * NNODES + dst0 + 4 * c, x, y, z, w);
  }
}

// ---------------------------------------------------------------------------
// Fallback (ws too small): memset + direct fp32 scatter.
// ---------------------------------------------------------------------------
__global__ __launch_bounds__(256) void scatter_kernel(
    const float* __restrict__ edge_attr,
    const float* __restrict__ ew,
    const int* __restrict__ path_idx,
    const int* __restrict__ path_lens,
    float* __restrict__ out) {
  __shared__ float w[LMAX * EDIM];
  if (threadIdx.x < LMAX * EDIM) w[threadIdx.x] = ew[threadIdx.x];
  __syncthreads();

  int p = blockIdx.x * 256 + threadIdx.x;
  if (p >= NPAIRS) return;

  int len = path_lens[p];
  len = min(max(len, 0), LMAX);

  const int* row = path_idx + (size_t)p * LMAX;
  float s = 0.f;
  for (int l = 0; l < len; ++l) {
    int idx = row[l];
    const float4* r = (const float4*)(edge_attr + (size_t)idx * EDIM);
    float4 a0 = r[0], a1 = r[1], a2 = r[2], a3 = r[3];
    const float* wl = &w[l * EDIM];
    s += a0.x * wl[0] + a0.y * wl[1] + a0.z * wl[2] + a0.w * wl[3] +
         a1.x * wl[4] + a1.y * wl[5] + a1.z * wl[6] + a1.w * wl[7] +
         a2.x * wl[8] + a2.y * wl[9] + a2.z * wl[10] + a2.w * wl[11] +
         a3.x * wl[12] + a3.y * wl[13] + a3.z * wl[14] + a3.w * wl[15];
  }
  float m = (len > 0) ? (s / (float)len) : 0.f;
  int src = p & (NNODES - 1);
  int dst = p >> 12;
  out[(size_t)src * NNODES + dst] = m;
}

extern "C" void kernel_launch(void* const* d_in, const int* in_sizes, int n_in,
                              void* d_out, int out_size, void* d_ws, size_t ws_size,
                              hipStream_t stream) {
  // setup_inputs order: x, edge_attr, edge_weights, path_idx, path_lens, pair_id
  const float* edge_attr = (const float*)d_in[1];
  const float* edge_w    = (const float*)d_in[2];
  const int*   path_idx  = (const int*)d_in[3];
  const int*   path_lens = (const int*)d_in[4];
  float* out = (float*)d_out;

  // ws layout: dots fp16 only (5MB).
  const size_t need = (size_t)LMAX * NEDGES * sizeof(__half);

  if (ws_size >= need) {
    __half* dots = (__half*)d_ws;

    dots_kernel<<<(NEDGES / 2 + 255) / 256, 256, 0, stream>>>(edge_attr, edge_w, dots);
    fused_mean_transpose<<<4096, 1024, 0, stream>>>(path_idx, path_lens, dots, out);
  } else {
    hipMemsetAsync(d_out, 0, (size_t)out_size * sizeof(float), stream);
    scatter_kernel<<<(NPAIRS + 255) / 256, 256, 0, stream>>>(
        edge_attr, edge_w, path_idx, path_lens, out);
  }
}

// Round 3
// 196.410 us; speedup vs baseline: 1.1057x; 1.1057x over previous
//
#include <hip/hip_runtime.h>
#include <hip/hip_fp16.h>

#define NNODES 4096
#define NEDGES 500000
#define NPAIRS 2000000
#define EDIM   16
#define LMAX   5

typedef int v4i __attribute__((ext_vector_type(4)));
typedef float v4f __attribute__((ext_vector_type(4)));

__device__ __forceinline__ v4i ntload4(const int* p) {
  return __builtin_nontemporal_load((const v4i*)p);
}
__device__ __forceinline__ void ntstore4(float* p, float x, float y, float z, float w) {
  v4f t = {x, y, z, w};
  __builtin_nontemporal_store(t, (v4f*)p);
}

// ---------------------------------------------------------------------------
// Kernel 0: dots[l*NEDGES + e] = fp16(dot(edge_attr[e,:], edge_weights[l,:]))
// ---------------------------------------------------------------------------
__global__ __launch_bounds__(256) void dots_kernel(
    const float* __restrict__ edge_attr,
    const float* __restrict__ ew,
    __half* __restrict__ dots) {
  __shared__ float w[LMAX * EDIM];
  int tid = threadIdx.x;
  if (tid < LMAX * EDIM) w[tid] = ew[tid];
  __syncthreads();

  int e0 = (blockIdx.x * 256 + tid) * 2;  // NEDGES even -> e0+1 always valid
  if (e0 >= NEDGES) return;

  const float4* ra = (const float4*)(edge_attr + (size_t)e0 * EDIM);
  float4 a0 = ra[0], a1 = ra[1], a2 = ra[2], a3 = ra[3];
  float4 b0 = ra[4], b1 = ra[5], b2 = ra[6], b3 = ra[7];  // edge e0+1
  float va[16] = {a0.x, a0.y, a0.z, a0.w, a1.x, a1.y, a1.z, a1.w,
                  a2.x, a2.y, a2.z, a2.w, a3.x, a3.y, a3.z, a3.w};
  float vb[16] = {b0.x, b0.y, b0.z, b0.w, b1.x, b1.y, b1.z, b1.w,
                  b2.x, b2.y, b2.z, b2.w, b3.x, b3.y, b3.z, b3.w};
#pragma unroll
  for (int l = 0; l < LMAX; ++l) {
    float da = 0.f, db = 0.f;
#pragma unroll
    for (int k = 0; k < EDIM; ++k) {
      da += va[k] * w[l * EDIM + k];
      db += vb[k] * w[l * EDIM + k];
    }
    __half2 h;
    h.x = __float2half(da);
    h.y = __float2half(db);
    *(__half2*)(dots + (size_t)l * NEDGES + e0) = h;  // e0 even -> 4B aligned
  }
}

// ---------------------------------------------------------------------------
// Fused mean + transpose, R3.
// R2 bug: heavy = (bid&1) put ALL heavy blocks on odd bids -> XCDs 1,3,5,7
// only (bid%8 round-robin) -> half the machine idle during gathers.
// R3: heavy blocks are bids 0..2047 (consecutive -> uniform over 8 XCDs),
// each a 64(dst) x 16(src) sub-tile (4 waves, <=64 VGPR via launch_bounds
// -> 8 blocks/CU = 32 waves/CU in the gather phase). Gathers are
// UNCONDITIONAL (path_idx entries are valid even past len) with masked
// accumulate -> no predication chains, all 20 gathers/thread in flight.
// Zero tiles (bids >= 2048) backfill behind the heavies.
// ---------------------------------------------------------------------------
__device__ __forceinline__ float pair_mean(
    const __half* __restrict__ dots, int len,
    int i0, int i1, int i2, int i3, int i4) {
  len = min(max(len, 0), LMAX);
  // Unconditional independent gathers (idx always in [0, NEDGES)).
  float v0 = __half2float(dots[i0]);
  float v1 = __half2float(dots[1 * NEDGES + i1]);
  float v2 = __half2float(dots[2 * NEDGES + i2]);
  float v3 = __half2float(dots[3 * NEDGES + i3]);
  float v4 = __half2float(dots[4 * NEDGES + i4]);
  float s = ((len > 0 ? v0 : 0.f) + (len > 1 ? v1 : 0.f)) +
            ((len > 2 ? v2 : 0.f) + (len > 3 ? v3 : 0.f)) +
            (len > 4 ? v4 : 0.f);
  return (len > 0) ? s / (float)len : 0.f;
}

#define NHEAVY 2048  // 512 tiles x 4 sub-tiles

__global__ __launch_bounds__(256, 8) void fused_mean_transpose(
    const int* __restrict__ path_idx,
    const int* __restrict__ path_lens,
    const __half* __restrict__ dots,
    float* __restrict__ out) {
  const int bid = blockIdx.x;
  const int tid = threadIdx.x;  // 0..255

  if (bid >= NHEAVY) {  // -------- pure-zero tile: stream 64x64 zeros
    int z = bid - NHEAVY;               // 0..3583
    int dst0 = (8 + (z >> 6)) * 64;     // dst tiles 8..63
    int src0 = (z & 63) * 64;
#pragma unroll
    for (int i = 0; i < 4; ++i) {
      int slot = tid + i * 256;  // 0..1023
      int a = slot >> 4;         // src row 0..63
      int c = slot & 15;         // float4 col
      ntstore4(out + (size_t)(src0 + a) * NNODES + dst0 + 4 * c, 0.f, 0.f, 0.f, 0.f);
    }
    return;
  }

  // -------- heavy sub-tile: 64 dst rows x 16 src cols
  const int t = bid >> 2;        // tile 0..511
  const int s = bid & 3;         // sub-tile 0..3
  const int dst0 = (t & 7) * 64; // dst tiles 0..7
  const int srcc0 = (t >> 3) * 64 + s * 16;  // first src col of sub-tile

  __shared__ float tile[16][65];  // [src_local][dst row]

  {
    const int a = tid >> 2;   // dst row offset 0..63
    const int c = tid & 3;    // float4 group within 16 src cols
    int p = (dst0 + a) * NNODES + srcc0 + 4 * c;  // multiple of 4
    float4 v = {0.f, 0.f, 0.f, 0.f};
    if (p < NPAIRS) {  // NPAIRS%4==0 -> all 4 pairs of the chunk valid
      v4i ln = ntload4(path_lens + p);
      const int* q = path_idx + (size_t)p * LMAX;  // 16B aligned (p%4==0)
      v4i A = ntload4(q);
      v4i B = ntload4(q + 4);
      v4i C = ntload4(q + 8);
      v4i D = ntload4(q + 12);
      v4i E = ntload4(q + 16);
      v.x = pair_mean(dots, ln[0], A[0], A[1], A[2], A[3], B[0]);
      v.y = pair_mean(dots, ln[1], B[1], B[2], B[3], C[0], C[1]);
      v.z = pair_mean(dots, ln[2], C[2], C[3], D[0], D[1], D[2]);
      v.w = pair_mean(dots, ln[3], D[3], E[0], E[1], E[2], E[3]);
    }
    tile[4 * c + 0][a] = v.x;
    tile[4 * c + 1][a] = v.y;
    tile[4 * c + 2][a] = v.z;
    tile[4 * c + 3][a] = v.w;
  }
  __syncthreads();
  {
    const int r = tid >> 4;   // src row offset 0..15
    const int c = tid & 15;   // float4 group along dst
    float x = tile[r][4 * c + 0];
    float y = tile[r][4 * c + 1];
    float z = tile[r][4 * c + 2];
    float w = tile[r][4 * c + 3];
    ntstore4(out + (size_t)(srcc0 + r) * NNODES + dst0 + 4 * c, x, y, z, w);
  }
}

// ---------------------------------------------------------------------------
// Fallback (ws too small): memset + direct fp32 scatter.
// ---------------------------------------------------------------------------
__global__ __launch_bounds__(256) void scatter_kernel(
    const float* __restrict__ edge_attr,
    const float* __restrict__ ew,
    const int* __restrict__ path_idx,
    const int* __restrict__ path_lens,
    float* __restrict__ out) {
  __shared__ float w[LMAX * EDIM];
  if (threadIdx.x < LMAX * EDIM) w[threadIdx.x] = ew[threadIdx.x];
  __syncthreads();

  int p = blockIdx.x * 256 + threadIdx.x;
  if (p >= NPAIRS) return;

  int len = path_lens[p];
  len = min(max(len, 0), LMAX);

  const int* row = path_idx + (size_t)p * LMAX;
  float s = 0.f;
  for (int l = 0; l < len; ++l) {
    int idx = row[l];
    const float4* r = (const float4*)(edge_attr + (size_t)idx * EDIM);
    float4 a0 = r[0], a1 = r[1], a2 = r[2], a3 = r[3];
    const float* wl = &w[l * EDIM];
    s += a0.x * wl[0] + a0.y * wl[1] + a0.z * wl[2] + a0.w * wl[3] +
         a1.x * wl[4] + a1.y * wl[5] + a1.z * wl[6] + a1.w * wl[7] +
         a2.x * wl[8] + a2.y * wl[9] + a2.z * wl[10] + a2.w * wl[11] +
         a3.x * wl[12] + a3.y * wl[13] + a3.z * wl[14] + a3.w * wl[15];
  }
  float m = (len > 0) ? (s / (float)len) : 0.f;
  int src = p & (NNODES - 1);
  int dst = p >> 12;
  out[(size_t)src * NNODES + dst] = m;
}

extern "C" void kernel_launch(void* const* d_in, const int* in_sizes, int n_in,
                              void* d_out, int out_size, void* d_ws, size_t ws_size,
                              hipStream_t stream) {
  // setup_inputs order: x, edge_attr, edge_weights, path_idx, path_lens, pair_id
  const float* edge_attr = (const float*)d_in[1];
  const float* edge_w    = (const float*)d_in[2];
  const int*   path_idx  = (const int*)d_in[3];
  const int*   path_lens = (const int*)d_in[4];
  float* out = (float*)d_out;

  // ws layout: dots fp16 only (5MB).
  const size_t need = (size_t)LMAX * NEDGES * sizeof(__half);

  if (ws_size >= need) {
    __half* dots = (__half*)d_ws;

    dots_kernel<<<(NEDGES / 2 + 255) / 256, 256, 0, stream>>>(edge_attr, edge_w, dots);
    // 2048 heavy sub-tile blocks first (bids 0..2047 -> uniform over XCDs),
    // then 3584 zero-tile blocks backfill.
    fused_mean_transpose<<<NHEAVY + 3584, 256, 0, stream>>>(path_idx, path_lens, dots, out);
  } else {
    hipMemsetAsync(d_out, 0, (size_t)out_size * sizeof(float), stream);
    scatter_kernel<<<(NPAIRS + 255) / 256, 256, 0, stream>>>(
        edge_attr, edge_w, path_idx, path_lens, out);
  }
}

// Round 4
// 183.491 us; speedup vs baseline: 1.1835x; 1.0704x over previous
//
#include <hip/hip_runtime.h>
#include <hip/hip_fp16.h>

#define NNODES 4096
#define NEDGES 500000
#define NPAIRS 2000000
#define EDIM   16
#define LMAX   5

typedef int v4i __attribute__((ext_vector_type(4)));
typedef float v4f __attribute__((ext_vector_type(4)));

__device__ __forceinline__ v4i ntload4(const int* p) {
  return __builtin_nontemporal_load((const v4i*)p);
}
__device__ __forceinline__ void ntstore4(float* p, float x, float y, float z, float w) {
  v4f t = {x, y, z, w};
  __builtin_nontemporal_store(t, (v4f*)p);
}

// ---------------------------------------------------------------------------
// Kernel 0: dots[l*NEDGES + e] = fp16(dot(edge_attr[e,:], edge_weights[l,:]))
// ---------------------------------------------------------------------------
__global__ __launch_bounds__(256) void dots_kernel(
    const float* __restrict__ edge_attr,
    const float* __restrict__ ew,
    __half* __restrict__ dots) {
  __shared__ float w[LMAX * EDIM];
  int tid = threadIdx.x;
  if (tid < LMAX * EDIM) w[tid] = ew[tid];
  __syncthreads();

  int e0 = (blockIdx.x * 256 + tid) * 2;  // NEDGES even -> e0+1 always valid
  if (e0 >= NEDGES) return;

  const float4* ra = (const float4*)(edge_attr + (size_t)e0 * EDIM);
  float4 a0 = ra[0], a1 = ra[1], a2 = ra[2], a3 = ra[3];
  float4 b0 = ra[4], b1 = ra[5], b2 = ra[6], b3 = ra[7];  // edge e0+1
  float va[16] = {a0.x, a0.y, a0.z, a0.w, a1.x, a1.y, a1.z, a1.w,
                  a2.x, a2.y, a2.z, a2.w, a3.x, a3.y, a3.z, a3.w};
  float vb[16] = {b0.x, b0.y, b0.z, b0.w, b1.x, b1.y, b1.z, b1.w,
                  b2.x, b2.y, b2.z, b2.w, b3.x, b3.y, b3.z, b3.w};
#pragma unroll
  for (int l = 0; l < LMAX; ++l) {
    float da = 0.f, db = 0.f;
#pragma unroll
    for (int k = 0; k < EDIM; ++k) {
      da += va[k] * w[l * EDIM + k];
      db += vb[k] * w[l * EDIM + k];
    }
    __half2 h;
    h.x = __float2half(da);
    h.y = __float2half(db);
    *(__half2*)(dots + (size_t)l * NEDGES + e0) = h;  // e0 even -> 4B aligned
  }
}

// ---------------------------------------------------------------------------
// Fused mean + transpose, R4 = R3 scheduling + R1 predicated gathers.
// R3 scheduling (keep): heavy blocks at consecutive bids 0..2047 -> uniform
//   over all 8 XCDs; 64(dst) x 16(src) sub-tiles, 256 threads, launch_bounds
//   (256,8) -> 8 blocks/CU = 32 waves/CU during the gather phase (Occ 73%).
// R3 regression (revert): UNCONDITIONAL gathers doubled random-gather lane
//   traffic (avg len = 2.5 of 5) -> FETCH 84->156MB, +24us. Exec-masked
//   (len>l ? load : 0) gathers are still independent in-flight VMEM ops but
//   masked lanes generate no transactions (R0/R1 counters prove it).
// ---------------------------------------------------------------------------
__device__ __forceinline__ float pair_mean(
    const __half* __restrict__ dots, int len,
    int i0, int i1, int i2, int i3, int i4) {
  len = min(max(len, 0), LMAX);
  // Exec-masked independent gathers: no transactions for invalid hops.
  float v0 = (len > 0) ? __half2float(dots[i0]) : 0.f;
  float v1 = (len > 1) ? __half2float(dots[1 * NEDGES + i1]) : 0.f;
  float v2 = (len > 2) ? __half2float(dots[2 * NEDGES + i2]) : 0.f;
  float v3 = (len > 3) ? __half2float(dots[3 * NEDGES + i3]) : 0.f;
  float v4 = (len > 4) ? __half2float(dots[4 * NEDGES + i4]) : 0.f;
  float s = ((v0 + v1) + (v2 + v3)) + v4;
  return (len > 0) ? s / (float)len : 0.f;
}

#define NHEAVY 2048  // 512 tiles x 4 sub-tiles

__global__ __launch_bounds__(256, 8) void fused_mean_transpose(
    const int* __restrict__ path_idx,
    const int* __restrict__ path_lens,
    const __half* __restrict__ dots,
    float* __restrict__ out) {
  const int bid = blockIdx.x;
  const int tid = threadIdx.x;  // 0..255

  if (bid >= NHEAVY) {  // -------- pure-zero tile: stream 64x64 zeros
    int z = bid - NHEAVY;               // 0..3583
    int dst0 = (8 + (z >> 6)) * 64;     // dst tiles 8..63
    int src0 = (z & 63) * 64;
#pragma unroll
    for (int i = 0; i < 4; ++i) {
      int slot = tid + i * 256;  // 0..1023
      int a = slot >> 4;         // src row 0..63
      int c = slot & 15;         // float4 col
      ntstore4(out + (size_t)(src0 + a) * NNODES + dst0 + 4 * c, 0.f, 0.f, 0.f, 0.f);
    }
    return;
  }

  // -------- heavy sub-tile: 64 dst rows x 16 src cols
  const int t = bid >> 2;        // tile 0..511
  const int s = bid & 3;         // sub-tile 0..3
  const int dst0 = (t & 7) * 64; // dst tiles 0..7
  const int srcc0 = (t >> 3) * 64 + s * 16;  // first src col of sub-tile

  __shared__ float tile[16][65];  // [src_local][dst row]

  {
    const int a = tid >> 2;   // dst row offset 0..63
    const int c = tid & 3;    // float4 group within 16 src cols
    int p = (dst0 + a) * NNODES + srcc0 + 4 * c;  // multiple of 4
    float4 v = {0.f, 0.f, 0.f, 0.f};
    if (p < NPAIRS) {  // NPAIRS%4==0 -> all 4 pairs of the chunk valid
      v4i ln = ntload4(path_lens + p);
      const int* q = path_idx + (size_t)p * LMAX;  // 16B aligned (p%4==0)
      v4i A = ntload4(q);
      v4i B = ntload4(q + 4);
      v4i C = ntload4(q + 8);
      v4i D = ntload4(q + 12);
      v4i E = ntload4(q + 16);
      v.x = pair_mean(dots, ln[0], A[0], A[1], A[2], A[3], B[0]);
      v.y = pair_mean(dots, ln[1], B[1], B[2], B[3], C[0], C[1]);
      v.z = pair_mean(dots, ln[2], C[2], C[3], D[0], D[1], D[2]);
      v.w = pair_mean(dots, ln[3], D[3], E[0], E[1], E[2], E[3]);
    }
    tile[4 * c + 0][a] = v.x;
    tile[4 * c + 1][a] = v.y;
    tile[4 * c + 2][a] = v.z;
    tile[4 * c + 3][a] = v.w;
  }
  __syncthreads();
  {
    const int r = tid >> 4;   // src row offset 0..15
    const int c = tid & 15;   // float4 group along dst
    float x = tile[r][4 * c + 0];
    float y = tile[r][4 * c + 1];
    float z = tile[r][4 * c + 2];
    float w = tile[r][4 * c + 3];
    ntstore4(out + (size_t)(srcc0 + r) * NNODES + dst0 + 4 * c, x, y, z, w);
  }
}

// ---------------------------------------------------------------------------
// Fallback (ws too small): memset + direct fp32 scatter.
// ---------------------------------------------------------------------------
__global__ __launch_bounds__(256) void scatter_kernel(
    const float* __restrict__ edge_attr,
    const float* __restrict__ ew,
    const int* __restrict__ path_idx,
    const int* __restrict__ path_lens,
    float* __restrict__ out) {
  __shared__ float w[LMAX * EDIM];
  if (threadIdx.x < LMAX * EDIM) w[threadIdx.x] = ew[threadIdx.x];
  __syncthreads();

  int p = blockIdx.x * 256 + threadIdx.x;
  if (p >= NPAIRS) return;

  int len = path_lens[p];
  len = min(max(len, 0), LMAX);

  const int* row = path_idx + (size_t)p * LMAX;
  float s = 0.f;
  for (int l = 0; l < len; ++l) {
    int idx = row[l];
    const float4* r = (const float4*)(edge_attr + (size_t)idx * EDIM);
    float4 a0 = r[0], a1 = r[1], a2 = r[2], a3 = r[3];
    const float* wl = &w[l * EDIM];
    s += a0.x * wl[0] + a0.y * wl[1] + a0.z * wl[2] + a0.w * wl[3] +
         a1.x * wl[4] + a1.y * wl[5] + a1.z * wl[6] + a1.w * wl[7] +
         a2.x * wl[8] + a2.y * wl[9] + a2.z * wl[10] + a2.w * wl[11] +
         a3.x * wl[12] + a3.y * wl[13] + a3.z * wl[14] + a3.w * wl[15];
  }
  float m = (len > 0) ? (s / (float)len) : 0.f;
  int src = p & (NNODES - 1);
  int dst = p >> 12;
  out[(size_t)src * NNODES + dst] = m;
}

extern "C" void kernel_launch(void* const* d_in, const int* in_sizes, int n_in,
                              void* d_out, int out_size, void* d_ws, size_t ws_size,
                              hipStream_t stream) {
  // setup_inputs order: x, edge_attr, edge_weights, path_idx, path_lens, pair_id
  const float* edge_attr = (const float*)d_in[1];
  const float* edge_w    = (const float*)d_in[2];
  const int*   path_idx  = (const int*)d_in[3];
  const int*   path_lens = (const int*)d_in[4];
  float* out = (float*)d_out;

  // ws layout: dots fp16 only (5MB).
  const size_t need = (size_t)LMAX * NEDGES * sizeof(__half);

  if (ws_size >= need) {
    __half* dots = (__half*)d_ws;

    dots_kernel<<<(NEDGES / 2 + 255) / 256, 256, 0, stream>>>(edge_attr, edge_w, dots);
    // 2048 heavy sub-tile blocks first (bids 0..2047 -> uniform over XCDs),
    // then 3584 zero-tile blocks backfill.
    fused_mean_transpose<<<NHEAVY + 3584, 256, 0, stream>>>(path_idx, path_lens, dots, out);
  } else {
    hipMemsetAsync(d_out, 0, (size_t)out_size * sizeof(float), stream);
    scatter_kernel<<<(NPAIRS + 255) / 256, 256, 0, stream>>>(
        edge_attr, edge_w, path_idx, path_lens, out);
  }
}

// Round 5
// 175.465 us; speedup vs baseline: 1.2377x; 1.0457x over previous
//
#include <hip/hip_runtime.h>
#include <hip/hip_fp16.h>

#define NNODES 4096
#define NEDGES 500000
#define NPAIRS 2000000
#define EDIM   16
#define LMAX   5

typedef int v4i __attribute__((ext_vector_type(4)));
typedef float v4f __attribute__((ext_vector_type(4)));

__device__ __forceinline__ v4i ntload4(const int* p) {
  return __builtin_nontemporal_load((const v4i*)p);
}
__device__ __forceinline__ void ntstore4(float* p, float x, float y, float z, float w) {
  v4f t = {x, y, z, w};
  __builtin_nontemporal_store(t, (v4f*)p);
}

// ---------------------------------------------------------------------------
// Kernel 0: dots[l*NEDGES + e] = fp16(dot(edge_attr[e,:], edge_weights[l,:]))
// ---------------------------------------------------------------------------
__global__ __launch_bounds__(256) void dots_kernel(
    const float* __restrict__ edge_attr,
    const float* __restrict__ ew,
    __half* __restrict__ dots) {
  __shared__ float w[LMAX * EDIM];
  int tid = threadIdx.x;
  if (tid < LMAX * EDIM) w[tid] = ew[tid];
  __syncthreads();

  int e0 = (blockIdx.x * 256 + tid) * 2;  // NEDGES even -> e0+1 always valid
  if (e0 >= NEDGES) return;

  const float4* ra = (const float4*)(edge_attr + (size_t)e0 * EDIM);
  float4 a0 = ra[0], a1 = ra[1], a2 = ra[2], a3 = ra[3];
  float4 b0 = ra[4], b1 = ra[5], b2 = ra[6], b3 = ra[7];  // edge e0+1
  float va[16] = {a0.x, a0.y, a0.z, a0.w, a1.x, a1.y, a1.z, a1.w,
                  a2.x, a2.y, a2.z, a2.w, a3.x, a3.y, a3.z, a3.w};
  float vb[16] = {b0.x, b0.y, b0.z, b0.w, b1.x, b1.y, b1.z, b1.w,
                  b2.x, b2.y, b2.z, b2.w, b3.x, b3.y, b3.z, b3.w};
#pragma unroll
  for (int l = 0; l < LMAX; ++l) {
    float da = 0.f, db = 0.f;
#pragma unroll
    for (int k = 0; k < EDIM; ++k) {
      da += va[k] * w[l * EDIM + k];
      db += vb[k] * w[l * EDIM + k];
    }
    __half2 h;
    h.x = __float2half(da);
    h.y = __float2half(db);
    *(__half2*)(dots + (size_t)l * NEDGES + e0) = h;  // e0 even -> 4B aligned
  }
}

// ---------------------------------------------------------------------------
// Fused mean + transpose, R5: 2-chunk software pipeline per thread.
// R4 post-mortem: VGPR_Count=16 < the 24 needed to hold ln+A..E -> compiler
// SERIALIZED the streaming loads (2-3 in flight per wave); occupancy (31% R1
// vs 65% R4) didn't move the needle -> bound by per-wave in-flight depth,
// not wave count. Fix: each thread owns TWO 4-pair chunks; all 12 NT dwordx4
// loads issue back-to-back (chunk1 streams fly under chunk0 gathers), then
// 10 predicated gathers. launch_bounds(256,6) (<=85 VGPR) so regalloc keeps
// the loads live. Sub-tiles are 32(dst) x 64(src) -> contiguous 1280B idx
// runs (R4's 16-wide tiles wasted +13MB FETCH on 320B segments).
// Heavy blocks = 1024 consecutive bids (XCD-uniform); 3584 zero blocks
// backfill co-resident, streaming NT writes under gather stalls.
// ---------------------------------------------------------------------------
__device__ __forceinline__ float pair_mean(
    const __half* __restrict__ dots, int len,
    int i0, int i1, int i2, int i3, int i4) {
  len = min(max(len, 0), LMAX);
  // Exec-masked independent gathers: no transactions for invalid hops.
  float v0 = (len > 0) ? __half2float(dots[i0]) : 0.f;
  float v1 = (len > 1) ? __half2float(dots[1 * NEDGES + i1]) : 0.f;
  float v2 = (len > 2) ? __half2float(dots[2 * NEDGES + i2]) : 0.f;
  float v3 = (len > 3) ? __half2float(dots[3 * NEDGES + i3]) : 0.f;
  float v4 = (len > 4) ? __half2float(dots[4 * NEDGES + i4]) : 0.f;
  float s = ((v0 + v1) + (v2 + v3)) + v4;
  return (len > 0) ? s / (float)len : 0.f;
}

#define NHEAVY 1024  // 512 tiles x 2 half-tiles (32 dst rows x 64 src cols)

__global__ __launch_bounds__(256, 6) void fused_mean_transpose(
    const int* __restrict__ path_idx,
    const int* __restrict__ path_lens,
    const __half* __restrict__ dots,
    float* __restrict__ out) {
  const int bid = blockIdx.x;
  const int tid = threadIdx.x;  // 0..255

  if (bid >= NHEAVY) {  // -------- pure-zero tile: stream 64x64 zeros
    int z = bid - NHEAVY;               // 0..3583
    int dst0 = (8 + (z >> 6)) * 64;     // dst tiles 8..63
    int src0 = (z & 63) * 64;
#pragma unroll
    for (int i = 0; i < 4; ++i) {
      int slot = tid + i * 256;  // 0..1023
      int a = slot >> 4;         // src row 0..63
      int c = slot & 15;         // float4 col
      ntstore4(out + (size_t)(src0 + a) * NNODES + dst0 + 4 * c, 0.f, 0.f, 0.f, 0.f);
    }
    return;
  }

  // -------- heavy half-tile: 32 dst rows x 64 src cols
  const int tt = bid >> 1;                 // tile 0..511
  const int h  = bid & 1;                  // half 0..1
  const int dst0 = (tt & 7) * 64 + h * 32; // dst rows 0..511
  const int src0 = (tt >> 3) * 64;

  __shared__ float tile[64][33];  // [src_local][dst_local(32)+pad]

  {
    const int a = tid >> 4;   // dst row (chunk0) 0..15; chunk1 = a+16
    const int c = tid & 15;   // float4 group along src
    // 16 threads per row x 80B = 1280B contiguous idx runs.
    int p0 = (dst0 + a) * NNODES + src0 + 4 * c;       // multiple of 4
    int p1 = p0 + 16 * NNODES;
    float4 v0 = {0.f, 0.f, 0.f, 0.f};
    float4 v1 = {0.f, 0.f, 0.f, 0.f};
    // p1 > p0, so (p1 valid) => (p0 valid). NPAIRS%4==0 and chunks are
    // row-contained -> whole-chunk validity checks are exact.
    if (p1 < NPAIRS) {
      // Issue ALL 12 streaming loads before any use.
      const int* q0 = path_idx + (size_t)p0 * LMAX;  // 16B aligned (p%4==0)
      const int* q1 = path_idx + (size_t)p1 * LMAX;
      v4i ln0 = ntload4(path_lens + p0);
      v4i ln1 = ntload4(path_lens + p1);
      v4i A0 = ntload4(q0);      v4i A1 = ntload4(q1);
      v4i B0 = ntload4(q0 + 4);  v4i B1 = ntload4(q1 + 4);
      v4i C0 = ntload4(q0 + 8);  v4i C1 = ntload4(q1 + 8);
      v4i D0 = ntload4(q0 + 12); v4i D1 = ntload4(q1 + 12);
      v4i E0 = ntload4(q0 + 16); v4i E1 = ntload4(q1 + 16);
      v0.x = pair_mean(dots, ln0[0], A0[0], A0[1], A0[2], A0[3], B0[0]);
      v0.y = pair_mean(dots, ln0[1], B0[1], B0[2], B0[3], C0[0], C0[1]);
      v0.z = pair_mean(dots, ln0[2], C0[2], C0[3], D0[0], D0[1], D0[2]);
      v0.w = pair_mean(dots, ln0[3], D0[3], E0[0], E0[1], E0[2], E0[3]);
      v1.x = pair_mean(dots, ln1[0], A1[0], A1[1], A1[2], A1[3], B1[0]);
      v1.y = pair_mean(dots, ln1[1], B1[1], B1[2], B1[3], C1[0], C1[1]);
      v1.z = pair_mean(dots, ln1[2], C1[2], C1[3], D1[0], D1[1], D1[2]);
      v1.w = pair_mean(dots, ln1[3], D1[3], E1[0], E1[1], E1[2], E1[3]);
    } else if (p0 < NPAIRS) {  // boundary half-tile (rare)
      const int* q0 = path_idx + (size_t)p0 * LMAX;
      v4i ln0 = ntload4(path_lens + p0);
      v4i A0 = ntload4(q0);
      v4i B0 = ntload4(q0 + 4);
      v4i C0 = ntload4(q0 + 8);
      v4i D0 = ntload4(q0 + 12);
      v4i E0 = ntload4(q0 + 16);
      v0.x = pair_mean(dots, ln0[0], A0[0], A0[1], A0[2], A0[3], B0[0]);
      v0.y = pair_mean(dots, ln0[1], B0[1], B0[2], B0[3], C0[0], C0[1]);
      v0.z = pair_mean(dots, ln0[2], C0[2], C0[3], D0[0], D0[1], D0[2]);
      v0.w = pair_mean(dots, ln0[3], D0[3], E0[0], E0[1], E0[2], E0[3]);
    }
    // 2-way bank aliasing max on these scalar writes (free).
    tile[4 * c + 0][a] = v0.x;
    tile[4 * c + 1][a] = v0.y;
    tile[4 * c + 2][a] = v0.z;
    tile[4 * c + 3][a] = v0.w;
    tile[4 * c + 0][a + 16] = v1.x;
    tile[4 * c + 1][a + 16] = v1.y;
    tile[4 * c + 2][a + 16] = v1.z;
    tile[4 * c + 3][a + 16] = v1.w;
  }
  __syncthreads();
  {
    const int r  = tid >> 2;  // src row 0..63
    const int cc = tid & 3;   // float4 group along dst (0..3); +16 for second
    float x0 = tile[r][4 * cc + 0];
    float y0 = tile[r][4 * cc + 1];
    float z0 = tile[r][4 * cc + 2];
    float w0 = tile[r][4 * cc + 3];
    float x1 = tile[r][16 + 4 * cc + 0];
    float y1 = tile[r][16 + 4 * cc + 1];
    float z1 = tile[r][16 + 4 * cc + 2];
    float w1 = tile[r][16 + 4 * cc + 3];
    float* o = out + (size_t)(src0 + r) * NNODES + dst0;
    ntstore4(o + 4 * cc, x0, y0, z0, w0);
    ntstore4(o + 16 + 4 * cc, x1, y1, z1, w1);
  }
}

// ---------------------------------------------------------------------------
// Fallback (ws too small): memset + direct fp32 scatter.
// ---------------------------------------------------------------------------
__global__ __launch_bounds__(256) void scatter_kernel(
    const float* __restrict__ edge_attr,
    const float* __restrict__ ew,
    const int* __restrict__ path_idx,
    const int* __restrict__ path_lens,
    float* __restrict__ out) {
  __shared__ float w[LMAX * EDIM];
  if (threadIdx.x < LMAX * EDIM) w[threadIdx.x] = ew[threadIdx.x];
  __syncthreads();

  int p = blockIdx.x * 256 + threadIdx.x;
  if (p >= NPAIRS) return;

  int len = path_lens[p];
  len = min(max(len, 0), LMAX);

  const int* row = path_idx + (size_t)p * LMAX;
  float s = 0.f;
  for (int l = 0; l < len; ++l) {
    int idx = row[l];
    const float4* r = (const float4*)(edge_attr + (size_t)idx * EDIM);
    float4 a0 = r[0], a1 = r[1], a2 = r[2], a3 = r[3];
    const float* wl = &w[l * EDIM];
    s += a0.x * wl[0] + a0.y * wl[1] + a0.z * wl[2] + a0.w * wl[3] +
         a1.x * wl[4] + a1.y * wl[5] + a1.z * wl[6] + a1.w * wl[7] +
         a2.x * wl[8] + a2.y * wl[9] + a2.z * wl[10] + a2.w * wl[11] +
         a3.x * wl[12] + a3.y * wl[13] + a3.z * wl[14] + a3.w * wl[15];
  }
  float m = (len > 0) ? (s / (float)len) : 0.f;
  int src = p & (NNODES - 1);
  int dst = p >> 12;
  out[(size_t)src * NNODES + dst] = m;
}

extern "C" void kernel_launch(void* const* d_in, const int* in_sizes, int n_in,
                              void* d_out, int out_size, void* d_ws, size_t ws_size,
                              hipStream_t stream) {
  // setup_inputs order: x, edge_attr, edge_weights, path_idx, path_lens, pair_id
  const float* edge_attr = (const float*)d_in[1];
  const float* edge_w    = (const float*)d_in[2];
  const int*   path_idx  = (const int*)d_in[3];
  const int*   path_lens = (const int*)d_in[4];
  float* out = (float*)d_out;

  // ws layout: dots fp16 only (5MB).
  const size_t need = (size_t)LMAX * NEDGES * sizeof(__half);

  if (ws_size >= need) {
    __half* dots = (__half*)d_ws;

    dots_kernel<<<(NEDGES / 2 + 255) / 256, 256, 0, stream>>>(edge_attr, edge_w, dots);
    // 1024 heavy half-tile blocks first (consecutive bids -> uniform XCDs),
    // then 3584 zero-tile blocks backfill.
    fused_mean_transpose<<<NHEAVY + 3584, 256, 0, stream>>>(path_idx, path_lens, dots, out);
  } else {
    hipMemsetAsync(d_out, 0, (size_t)out_size * sizeof(float), stream);
    scatter_kernel<<<(NPAIRS + 255) / 256, 256, 0, stream>>>(
        edge_attr, edge_w, path_idx, path_lens, out);
  }
}